// Round 4
// baseline (352.408 us; speedup 1.0000x reference)
//
#include <hip/hip_runtime.h>
#include <stdint.h>

typedef unsigned short u16;
typedef unsigned int u32;
typedef __attribute__((ext_vector_type(8))) short short8;
typedef __attribute__((ext_vector_type(4))) float float4v;

#define Bb 4
#define Ss 256
#define Hh 768
#define NBASIC 4
#define NALL 64
#define GRID 512               // 2 blocks/CU on 256 CUs: residency guaranteed
#define MAGIC 0x1234ABCD

__device__ __forceinline__ float b2f(u16 h) {
    u32 u = ((u32)h) << 16;
    float f;
    __builtin_memcpy(&f, &u, 4);
    return f;
}
__device__ __forceinline__ u16 f2b(float f) {
    u32 u;
    __builtin_memcpy(&u, &f, 4);
    u = (u + 0x7fffu + ((u >> 16) & 1u)) >> 16;  // RNE
    return (u16)u;
}

// dtype probe: low 16 bits of first 64 words of h. Packed-bf16 N(0,1) data has
// bf16 exponent in [100,140] ~always (count~64); fp32 mantissa bits are uniform
// (E[count]~10). Threshold 40 separates at astronomical sigma.
__device__ __forceinline__ int detect_bf16(const u32* __restrict__ hw) {
    int cnt = 0;
#pragma unroll
    for (int k = 0; k < 64; ++k) {
        const int e = (int)((hw[k] >> 7) & 0xFFu);
        cnt += (e >= 100 && e <= 140) ? 1 : 0;
    }
    return cnt >= 40;
}

// grid barrier over poisoned ws: bar[0]=ready flag, bar[1+idx]=one-shot counter.
// Block 0 zeroes counters then release-stores MAGIC; arrivals acquire-spin on
// MAGIC before touching the counters. Safe under 0xAA re-poison every call.
__device__ __forceinline__ void gbar(int* bar, int idx) {
    __syncthreads();
    if (threadIdx.x == 0) {
        __threadfence();  // release this block's phase writes (agent scope)
        while (__hip_atomic_load(&bar[0], __ATOMIC_ACQUIRE, __HIP_MEMORY_SCOPE_AGENT) != MAGIC)
            __builtin_amdgcn_s_sleep(2);
        __hip_atomic_fetch_add(&bar[1 + idx], 1, __ATOMIC_ACQ_REL, __HIP_MEMORY_SCOPE_AGENT);
        while (__hip_atomic_load(&bar[1 + idx], __ATOMIC_ACQUIRE, __HIP_MEMORY_SCOPE_AGENT) < GRID)
            __builtin_amdgcn_s_sleep(2);
        __threadfence();  // acquire other blocks' phase writes
    }
    __syncthreads();
}

// 64x64 MFMA tile, BK=64, reg prefetch across barrier. aB/bB pre-offset by
// (row*stride + kk); k advances contiguously by s*64.
__device__ __forceinline__ void gemm_tile(const u16* __restrict__ aB,
                                          const u16* __restrict__ bB,
                                          int niter, u16* As, u16* Bs,
                                          float4v* acc, int t) {
    const int row = t >> 2, kk = (t & 3) * 16;
    const int w = t >> 6, l = t & 63, quad = l >> 4, l16 = l & 15;
#pragma unroll
    for (int c = 0; c < 4; ++c) acc[c] = (float4v){0.f, 0.f, 0.f, 0.f};
    uint4 a0 = *(const uint4*)aB;
    uint4 a1 = *(const uint4*)(aB + 8);
    uint4 b0 = *(const uint4*)bB;
    uint4 b1 = *(const uint4*)(bB + 8);
    for (int s = 0; s < niter; ++s) {
        __syncthreads();
        *(uint4*)(&As[row * 72 + kk]) = a0;
        *(uint4*)(&As[row * 72 + kk + 8]) = a1;
        *(uint4*)(&Bs[row * 72 + kk]) = b0;
        *(uint4*)(&Bs[row * 72 + kk + 8]) = b1;
        __syncthreads();
        if (s + 1 < niter) {
            a0 = *(const uint4*)(aB + (s + 1) * 64);
            a1 = *(const uint4*)(aB + (s + 1) * 64 + 8);
            b0 = *(const uint4*)(bB + (s + 1) * 64);
            b1 = *(const uint4*)(bB + (s + 1) * 64 + 8);
        }
#pragma unroll
        for (int k2 = 0; k2 < 64; k2 += 32) {
            const short8 af = *(const short8*)(&As[(16 * w + l16) * 72 + k2 + quad * 8]);
#pragma unroll
            for (int c = 0; c < 4; ++c) {
                const short8 bfr = *(const short8*)(&Bs[(16 * c + l16) * 72 + k2 + quad * 8]);
                acc[c] = __builtin_amdgcn_mfma_f32_16x16x32_bf16(af, bfr, acc[c], 0, 0, 0);
            }
        }
    }
}

// Single persistent kernel: phase A (prep) | gbar | phase B (pooled GEMM) |
// gbar | phase C (output GEMM, K-split by q) | gbar | phase D (5-way reduce).
__global__ __launch_bounds__(256, 2) void k_all(const void* __restrict__ h_raw,
                                                const int* __restrict__ rels,
                                                const void* __restrict__ basic_raw,
                                                const void* __restrict__ relw_raw,
                                                const void* __restrict__ selfw_raw,
                                                u16* __restrict__ pooled,
                                                u16* __restrict__ basicT,
                                                u16* __restrict__ hbf,
                                                u16* __restrict__ hT,
                                                u16* __restrict__ swbf,
                                                u16* __restrict__ coefC,
                                                float* __restrict__ partial,
                                                int* __restrict__ bar,
                                                void* __restrict__ outv) {
    __shared__ __align__(16) u16 As[64 * 72];
    __shared__ __align__(16) u16 Bs[64 * 72];

    const int t = threadIdx.x;
    const int bf = detect_bf16((const u32*)h_raw);

    if (blockIdx.x == 0 && t == 0) {
        __hip_atomic_store(&bar[1], 0, __ATOMIC_RELAXED, __HIP_MEMORY_SCOPE_AGENT);
        __hip_atomic_store(&bar[2], 0, __ATOMIC_RELAXED, __HIP_MEMORY_SCOPE_AGENT);
        __hip_atomic_store(&bar[3], 0, __ATOMIC_RELAXED, __HIP_MEMORY_SCOPE_AGENT);
        __hip_atomic_store(&bar[0], MAGIC, __ATOMIC_RELEASE, __HIP_MEMORY_SCOPE_AGENT);
    }

    // ---------------- phase A: prep ----------------
    // units: [0,2304) basicT transpose | [2304,3072) hT | [3072,4096) coefC
    //        [4096,7168) h cvt (fp32 inputs only) | [7168,9472) selfw cvt (fp32 only)
    {
        u16(*tile)[33] = (u16(*)[33])As;
        float* srelw = (float*)Bs;               // 1 KB
        u32* hist = (u32*)(Bs + 1024);           // past srelw
        const int nA = bf ? 4096 : 9472;
        for (int u = blockIdx.x; u < nA; u += GRID) {
            __syncthreads();  // LDS reuse across units
            if (u < 2304) {                       // basic transpose + cvt
                const int r = u;
                const int o0 = (r % 24) * 32, i0 = ((r / 24) % 24) * 32, q = r / 576;
                const int tx = t & 31, ty = t >> 5;
                const size_t base = (size_t)q * Hh * Hh;
#pragma unroll
                for (int rr = 0; rr < 4; ++rr) {
                    const size_t idx = base + (size_t)(i0 + ty + 8 * rr) * Hh + o0 + tx;
                    tile[ty + 8 * rr][tx] = bf ? ((const u16*)basic_raw)[idx]
                                               : f2b(((const float*)basic_raw)[idx]);
                }
                __syncthreads();
#pragma unroll
                for (int rr = 0; rr < 4; ++rr)
                    basicT[base + (size_t)(o0 + ty + 8 * rr) * Hh + i0 + tx] = tile[tx][ty + 8 * rr];
            } else if (u < 3072) {                // hT[b][o][j] = h[b][j][o]
                const int r = u - 2304;
                const int o0 = (r % 24) * 32, i0 = ((r / 24) % 8) * 32, b = r / 192;
                const int tx = t & 31, ty = t >> 5;
#pragma unroll
                for (int rr = 0; rr < 4; ++rr) {
                    const size_t idx = ((size_t)b * Ss + i0 + ty + 8 * rr) * Hh + o0 + tx;
                    tile[ty + 8 * rr][tx] = bf ? ((const u16*)h_raw)[idx]
                                               : f2b(((const float*)h_raw)[idx]);
                }
                __syncthreads();
#pragma unroll
                for (int rr = 0; rr < 4; ++rr)
                    hT[((size_t)b * Hh + o0 + ty + 8 * rr) * Ss + i0 + tx] = tile[tx][ty + 8 * rr];
            } else if (u < 4096) {                // coefC build: one unit per (b,i)
                const int r = u - 3072;
                const int i = r & 255, b = r >> 8;
                srelw[t] = bf ? b2f(((const u16*)relw_raw)[t]) : ((const float*)relw_raw)[t];
                if (t < NALL) hist[t] = 0u;
                __syncthreads();
                const int rfw = rels[(b * Ss + i) * Ss + t];  // rels[b,i,t]
                const int rcl = rels[(b * Ss + t) * Ss + i];  // rels[b,t,i]
                if (rfw > 0) atomicAdd(&hist[rfw], 1u);
                if (rcl > 0) atomicAdd(&hist[rcl + 32], 1u);
                __syncthreads();
                float c0 = 0.f, c1 = 0.f, c2 = 0.f, c3 = 0.f;
                if (rfw > 0) {
                    const float inv = 1.0f / (float)hist[rfw];
                    c0 += srelw[rfw * 4 + 0] * inv; c1 += srelw[rfw * 4 + 1] * inv;
                    c2 += srelw[rfw * 4 + 2] * inv; c3 += srelw[rfw * 4 + 3] * inv;
                }
                if (rcl > 0) {
                    const int rr = rcl + 32;
                    const float inv = 1.0f / (float)hist[rr];
                    c0 += srelw[rr * 4 + 0] * inv; c1 += srelw[rr * 4 + 1] * inv;
                    c2 += srelw[rr * 4 + 2] * inv; c3 += srelw[rr * 4 + 3] * inv;
                }
                const size_t base = ((size_t)(b * 4) * Ss + i) * Ss + t;
                coefC[base] = f2b(c0);
                coefC[base + (size_t)Ss * Ss] = f2b(c1);
                coefC[base + (size_t)2 * Ss * Ss] = f2b(c2);
                coefC[base + (size_t)3 * Ss * Ss] = f2b(c3);
            } else if (u < 7168) {                // h cvt (fp32 only)
                const int i = (u - 4096) * 256 + t;
                hbf[i] = f2b(((const float*)h_raw)[i]);
            } else {                              // selfw cvt (fp32 only)
                const int i = (u - 7168) * 256 + t;
                swbf[i] = f2b(((const float*)selfw_raw)[i]);
            }
        }
    }
    gbar(bar, 0);

    // ---------------- phase B: pooled[b,k] = coefC[b,k] @ h[b] ----------------
    {
        const int row = t >> 2, kk = (t & 3) * 16;
        const int w = t >> 6, l = t & 63, quad = l >> 4, l16 = l & 15;
        for (int u = blockIdx.x; u < 768; u += GRID) {
            const int o0 = (u % 12) * 64;
            const int i0 = ((u / 12) % 4) * 64;
            const int bk = u / 48;
            const int b = bk >> 2;
            const u16* aB = coefC + ((size_t)bk * Ss + i0 + row) * Ss + kk;
            const u16* bB = hT + ((size_t)b * Hh + o0 + row) * Ss + kk;
            float4v acc[4];
            gemm_tile(aB, bB, 4, As, Bs, acc, t);
#pragma unroll
            for (int c = 0; c < 4; ++c)
#pragma unroll
                for (int r = 0; r < 4; ++r) {
                    const int il = 16 * w + quad * 4 + r;
                    const int ol = 16 * c + l16;
                    pooled[((size_t)bk * Ss + i0 + il) * Hh + o0 + ol] = f2b(acc[c][r]);
                }
        }
    }
    gbar(bar, 1);

    // ---------------- phase C: partial[q][b] = A_q[b] @ B_q ----------------
    {
        const u16* heff = bf ? (const u16*)h_raw : hbf;
        const u16* seff = bf ? (const u16*)selfw_raw : swbf;
        const int row = t >> 2, kk = (t & 3) * 16;
        const int w = t >> 6, l = t & 63, quad = l >> 4, l16 = l & 15;
        for (int u = blockIdx.x; u < 960; u += GRID) {
            const int o0 = (u % 12) * 64;
            const int i0 = ((u / 12) % 4) * 64;
            const int z = u / 48;  // q*4+b
            const int b = z & 3, q = z >> 2;
            const u16* aB = (q < 4) ? pooled + (((size_t)(b * 4 + q)) * Ss + i0 + row) * Hh + kk
                                    : heff + ((size_t)b * Ss + i0 + row) * Hh + kk;
            const u16* bB = (q < 4) ? basicT + ((size_t)q * Hh + o0 + row) * Hh + kk
                                    : seff + (size_t)(o0 + row) * Hh + kk;
            float4v acc[4];
            gemm_tile(aB, bB, 12, As, Bs, acc, t);
#pragma unroll
            for (int c = 0; c < 4; ++c)
#pragma unroll
                for (int r = 0; r < 4; ++r) {
                    const int il = 16 * w + quad * 4 + r;
                    const int ol = 16 * c + l16;
                    partial[((size_t)z * Ss + i0 + il) * Hh + o0 + ol] = acc[c][r];
                }
        }
    }
    gbar(bar, 2);

    // ---------------- phase D: out = sum_q partial[q] ----------------
    {
        const size_t slice = (size_t)Bb * Ss * Hh;  // 786432
        for (int u = blockIdx.x; u < 768; u += GRID) {
            const size_t idx = ((size_t)u * 256 + t) * 4;
            float4 s = *(const float4*)(partial + idx);
#pragma unroll
            for (int q = 1; q < 5; ++q) {
                const float4 p = *(const float4*)(partial + q * slice + idx);
                s.x += p.x; s.y += p.y; s.z += p.z; s.w += p.w;
            }
            if (bf) {
                const u32 lo = (u32)f2b(s.x) | ((u32)f2b(s.y) << 16);
                const u32 hi = (u32)f2b(s.z) | ((u32)f2b(s.w) << 16);
                *(uint2*)((u16*)outv + idx) = make_uint2(lo, hi);
            } else {
                *(float4*)((float*)outv + idx) = s;
            }
        }
    }
}

extern "C" void kernel_launch(void* const* d_in, const int* in_sizes, int n_in,
                              void* d_out, int out_size, void* d_ws, size_t ws_size,
                              hipStream_t stream) {
    const void* h_raw = d_in[0];             // [4,256,768]
    const int* rels = (const int*)d_in[1];   // [4,256,256] i32
    const void* basic_raw = d_in[2];         // [4,768,768]
    const void* relw_raw = d_in[3];          // [64,4]
    const void* selfw_raw = d_in[4];         // [768,768] (out,in)

    // ws layout (u16 elems; all 16B-aligned)
    u16* pooled = (u16*)d_ws;                             // 3,145,728
    u16* basicT = pooled + (size_t)Bb * 4 * Ss * Hh;      // 2,359,296
    u16* hbf    = basicT + (size_t)NBASIC * Hh * Hh;      //   786,432
    u16* hT     = hbf + (size_t)Bb * Ss * Hh;             //   786,432
    u16* swbf   = hT + (size_t)Bb * Hh * Ss;              //   589,824
    u16* coefC  = swbf + (size_t)Hh * Hh;                 // 1,048,576
    float* partial = (float*)(coefC + (size_t)Bb * 4 * Ss * Ss);  // 3,932,160 f32
    int* bar = (int*)(partial + (size_t)5 * Bb * Ss * Hh);        // 4 ints

    k_all<<<GRID, 256, 0, stream>>>(h_raw, rels, basic_raw, relw_raw, selfw_raw,
                                    pooled, basicT, hbf, hT, swbf, coefC,
                                    partial, bar, d_out);
}

// Round 7
// 108.326 us; speedup vs baseline: 3.2532x; 3.2532x over previous
//
#include <hip/hip_runtime.h>
#include <stdint.h>

typedef unsigned short u16;
typedef unsigned int u32;
typedef __attribute__((ext_vector_type(8))) short short8;
typedef __attribute__((ext_vector_type(4))) float float4v;

#define Bb 4
#define Ss 256
#define Hh 768
#define NALL 64

// NOTE (r7): inputs/outputs are FP32 (reference dtype). r1/r5/r6 NaN'd by
// reading fp32 buffers as bf16; r2-r4 passed only because their runtime
// detector chose the fp32 path. All global input reads below are float,
// converted to bf16 in registers during LDS staging.

__device__ __forceinline__ float b2f(u16 h) {
    u32 u = ((u32)h) << 16;
    float f;
    __builtin_memcpy(&f, &u, 4);
    return f;
}
__device__ __forceinline__ u16 f2b(float f) {
    u32 u;
    __builtin_memcpy(&u, &f, 4);
    u = (u + 0x7fffu + ((u >> 16) & 1u)) >> 16;  // RNE
    return (u16)u;
}
union pk8 { uint4 v; u16 e[8]; };
__device__ __forceinline__ uint4 cvt8(float4 f0, float4 f1) {
    pk8 r;
    r.e[0] = f2b(f0.x); r.e[1] = f2b(f0.y); r.e[2] = f2b(f0.z); r.e[3] = f2b(f0.w);
    r.e[4] = f2b(f1.x); r.e[5] = f2b(f1.y); r.e[6] = f2b(f1.z); r.e[7] = f2b(f1.w);
    return r.v;
}

// 64x64 MFMA tile over fp32 sources, BK=64, contiguous-K, reg prefetch,
// f32->bf16 conversion folded into LDS staging.
__device__ __forceinline__ void gemm_tile(const float* __restrict__ aB,
                                          const float* __restrict__ bB,
                                          int niter, u16* As, u16* Bs,
                                          float4v* acc, int t) {
    const int row = t >> 2, kk = (t & 3) * 16;
    const int w = t >> 6, l = t & 63, quad = l >> 4, l16 = l & 15;
#pragma unroll
    for (int c = 0; c < 4; ++c) acc[c] = (float4v){0.f, 0.f, 0.f, 0.f};
    float4 a0 = *(const float4*)aB, a1 = *(const float4*)(aB + 4);
    float4 a2 = *(const float4*)(aB + 8), a3 = *(const float4*)(aB + 12);
    float4 b0 = *(const float4*)bB, b1 = *(const float4*)(bB + 4);
    float4 b2 = *(const float4*)(bB + 8), b3 = *(const float4*)(bB + 12);
    for (int s = 0; s < niter; ++s) {
        __syncthreads();
        *(uint4*)(&As[row * 72 + kk]) = cvt8(a0, a1);
        *(uint4*)(&As[row * 72 + kk + 8]) = cvt8(a2, a3);
        *(uint4*)(&Bs[row * 72 + kk]) = cvt8(b0, b1);
        *(uint4*)(&Bs[row * 72 + kk + 8]) = cvt8(b2, b3);
        __syncthreads();
        if (s + 1 < niter) {
            const float* ap = aB + (s + 1) * 64;
            const float* bp = bB + (s + 1) * 64;
            a0 = *(const float4*)ap; a1 = *(const float4*)(ap + 4);
            a2 = *(const float4*)(ap + 8); a3 = *(const float4*)(ap + 12);
            b0 = *(const float4*)bp; b1 = *(const float4*)(bp + 4);
            b2 = *(const float4*)(bp + 8); b3 = *(const float4*)(bp + 12);
        }
#pragma unroll
        for (int k2 = 0; k2 < 64; k2 += 32) {
            const short8 af = *(const short8*)(&As[(16 * w + l16) * 72 + k2 + quad * 8]);
#pragma unroll
            for (int c = 0; c < 4; ++c) {
                const short8 bfr = *(const short8*)(&Bs[(16 * c + l16) * 72 + k2 + quad * 8]);
                acc[c] = __builtin_amdgcn_mfma_f32_16x16x32_bf16(af, bfr, acc[c], 0, 0, 0);
            }
        }
    }
}

// ---- L1: three independent region types ----
//  z in [0,768):    Gt[b,q](768x256) = (h[b] @ basic[q])^T  — B transposed in LDS
//  z in [768,960):  S[b](256x768) = h[b] @ selfw^T           — selfw already (out,in)
//  z in [960,1984): coefC[b,q](256x256) build (hist + relw)
__global__ __launch_bounds__(256, 4) void k_phase1(const float* __restrict__ h,
                                                   const int* __restrict__ rels,
                                                   const float* __restrict__ basic,
                                                   const float* __restrict__ relw,
                                                   const float* __restrict__ selfw,
                                                   u16* __restrict__ coefC,
                                                   u16* __restrict__ Gt,
                                                   u16* __restrict__ S) {
    __shared__ __align__(16) u16 As[64 * 72];
    __shared__ __align__(16) u16 Bs[64 * 72];
    const int t = threadIdx.x;
    const int z = blockIdx.x;
    const int row = t >> 2, kk = (t & 3) * 16;
    const int w = t >> 6, l = t & 63, quad = l >> 4, l16 = l & 15;

    if (z < 768) {
        // Gt unit: M = j (h rows), K = i, N = o. bk = b*4+q.
        const int ot = z % 12, jt = (z / 12) % 4, bk = z / 48;
        const int b = bk >> 2, q = bk & 3;
        const float* aB = h + ((size_t)b * Ss + jt * 64 + row) * Hh + kk;
        const float* bp = basic + ((size_t)q * Hh + row) * Hh + ot * 64 + kk;  // rows i, cols o

        float4v acc[4];
#pragma unroll
        for (int c = 0; c < 4; ++c) acc[c] = (float4v){0.f, 0.f, 0.f, 0.f};
        float4 a0 = *(const float4*)aB, a1 = *(const float4*)(aB + 4);
        float4 a2 = *(const float4*)(aB + 8), a3 = *(const float4*)(aB + 12);
        float4 b0 = *(const float4*)bp, b1 = *(const float4*)(bp + 4);
        float4 b2 = *(const float4*)(bp + 8), b3 = *(const float4*)(bp + 12);

        for (int s = 0; s < 12; ++s) {
            __syncthreads();
            *(uint4*)(&As[row * 72 + kk]) = cvt8(a0, a1);
            *(uint4*)(&As[row * 72 + kk + 8]) = cvt8(a2, a3);
            {   // transpose scatter: Bs[n=o_local][k=i_local]
                pk8 t0, t1;
                t0.v = cvt8(b0, b1);
                t1.v = cvt8(b2, b3);
#pragma unroll
                for (int m = 0; m < 8; ++m) Bs[(kk + m) * 72 + row] = t0.e[m];
#pragma unroll
                for (int m = 0; m < 8; ++m) Bs[(kk + 8 + m) * 72 + row] = t1.e[m];
            }
            __syncthreads();
            if (s + 1 < 12) {
                const float* ap = aB + (s + 1) * 64;
                const float* bq = bp + (size_t)(s + 1) * 64 * Hh;
                a0 = *(const float4*)ap; a1 = *(const float4*)(ap + 4);
                a2 = *(const float4*)(ap + 8); a3 = *(const float4*)(ap + 12);
                b0 = *(const float4*)bq; b1 = *(const float4*)(bq + 4);
                b2 = *(const float4*)(bq + 8); b3 = *(const float4*)(bq + 12);
            }
#pragma unroll
            for (int k2 = 0; k2 < 64; k2 += 32) {
                const short8 af = *(const short8*)(&As[(16 * w + l16) * 72 + k2 + quad * 8]);
#pragma unroll
                for (int c = 0; c < 4; ++c) {
                    const short8 bfr = *(const short8*)(&Bs[(16 * c + l16) * 72 + k2 + quad * 8]);
                    acc[c] = __builtin_amdgcn_mfma_f32_16x16x32_bf16(af, bfr, acc[c], 0, 0, 0);
                }
            }
        }
        // transposed epilogue through LDS: Gt[o][j]
        __syncthreads();
#pragma unroll
        for (int c = 0; c < 4; ++c)
#pragma unroll
            for (int r = 0; r < 4; ++r)
                As[(16 * c + l16) * 72 + 16 * w + quad * 4 + r] = f2b(acc[c][r]);
        __syncthreads();
#pragma unroll
        for (int uu = 0; uu < 2; ++uu) {
            const int u = t + uu * 256;
            const int oo = u >> 3, ch = u & 7;
            *(uint4*)(&Gt[((size_t)bk * Hh + ot * 64 + oo) * Ss + jt * 64 + ch * 8]) =
                *(const uint4*)(&As[oo * 72 + ch * 8]);
        }
    } else if (z < 960) {
        // S unit: S[b] = h[b] @ selfw^T
        const int u = z - 768;
        const int ot = u % 12, it = (u / 12) % 4, b = u / 48;
        const float* aB = h + ((size_t)b * Ss + it * 64 + row) * Hh + kk;
        const float* bB = selfw + (size_t)(ot * 64 + row) * Hh + kk;
        float4v acc[4];
        gemm_tile(aB, bB, 12, As, Bs, acc, t);
#pragma unroll
        for (int c = 0; c < 4; ++c)
#pragma unroll
            for (int r = 0; r < 4; ++r) {
                const int il = 16 * w + quad * 4 + r;
                const int ol = 16 * c + l16;
                S[((size_t)b * Ss + it * 64 + il) * Hh + ot * 64 + ol] = f2b(acc[c][r]);
            }
    } else {
        // coefC unit: one block per (b,i)  [verified r2 logic, relw now fp32]
        float* srelw = (float*)As;
        u32* hist = (u32*)Bs;
        const int r = z - 960;
        const int i = r & 255, b = r >> 8;
        srelw[t] = relw[t];
        if (t < NALL) hist[t] = 0u;
        __syncthreads();
        const int rfw = rels[(b * Ss + i) * Ss + t];  // rels[b,i,t]
        const int rcl = rels[(b * Ss + t) * Ss + i];  // rels[b,t,i]
        if (rfw > 0) atomicAdd(&hist[rfw], 1u);
        if (rcl > 0) atomicAdd(&hist[rcl + 32], 1u);
        __syncthreads();
        float c0 = 0.f, c1 = 0.f, c2 = 0.f, c3 = 0.f;
        if (rfw > 0) {
            const float inv = 1.0f / (float)hist[rfw];
            c0 += srelw[rfw * 4 + 0] * inv; c1 += srelw[rfw * 4 + 1] * inv;
            c2 += srelw[rfw * 4 + 2] * inv; c3 += srelw[rfw * 4 + 3] * inv;
        }
        if (rcl > 0) {
            const int rr = rcl + 32;
            const float inv = 1.0f / (float)hist[rr];
            c0 += srelw[rr * 4 + 0] * inv; c1 += srelw[rr * 4 + 1] * inv;
            c2 += srelw[rr * 4 + 2] * inv; c3 += srelw[rr * 4 + 3] * inv;
        }
        const size_t base = ((size_t)(b * 4) * Ss + i) * Ss + t;
        coefC[base] = f2b(c0);
        coefC[base + (size_t)Ss * Ss] = f2b(c1);
        coefC[base + (size_t)2 * Ss * Ss] = f2b(c2);
        coefC[base + (size_t)3 * Ss * Ss] = f2b(c3);
    }
}

// ---- L2: out[b] = sum_q coefC[b,q] @ Gt[b,q]^T + S[b], K = 4*256, out fp32 ----
__global__ __launch_bounds__(256, 4) void k_phase2(const u16* __restrict__ coefC,
                                                   const u16* __restrict__ Gt,
                                                   const u16* __restrict__ S,
                                                   float* __restrict__ out) {
    __shared__ __align__(16) u16 As[64 * 72];
    __shared__ __align__(16) u16 Bs[64 * 72];
    const int z = blockIdx.x;
    const int ot = z % 12, it = (z / 12) % 4, b = z / 48;
    const int t = threadIdx.x;
    const int row = t >> 2, kk = (t & 3) * 16;
    const int w = t >> 6, l = t & 63, quad = l >> 4, l16 = l & 15;

    auto aa = [&](int s) -> const u16* {
        return coefC + ((size_t)(b * 4 + (s >> 2)) * Ss + it * 64 + row) * Ss + (s & 3) * 64 + kk;
    };
    auto bb = [&](int s) -> const u16* {
        return Gt + ((size_t)(b * 4 + (s >> 2)) * Hh + ot * 64 + row) * Ss + (s & 3) * 64 + kk;
    };

    float4v acc[4];
#pragma unroll
    for (int c = 0; c < 4; ++c) acc[c] = (float4v){0.f, 0.f, 0.f, 0.f};
    uint4 a0 = *(const uint4*)aa(0);
    uint4 a1 = *(const uint4*)(aa(0) + 8);
    uint4 b0 = *(const uint4*)bb(0);
    uint4 b1 = *(const uint4*)(bb(0) + 8);

    for (int s = 0; s < 16; ++s) {
        __syncthreads();
        *(uint4*)(&As[row * 72 + kk]) = a0;
        *(uint4*)(&As[row * 72 + kk + 8]) = a1;
        *(uint4*)(&Bs[row * 72 + kk]) = b0;
        *(uint4*)(&Bs[row * 72 + kk + 8]) = b1;
        __syncthreads();
        if (s + 1 < 16) {
            const u16* ap = aa(s + 1);
            const u16* bp = bb(s + 1);
            a0 = *(const uint4*)ap;
            a1 = *(const uint4*)(ap + 8);
            b0 = *(const uint4*)bp;
            b1 = *(const uint4*)(bp + 8);
        }
#pragma unroll
        for (int k2 = 0; k2 < 64; k2 += 32) {
            const short8 af = *(const short8*)(&As[(16 * w + l16) * 72 + k2 + quad * 8]);
#pragma unroll
            for (int c = 0; c < 4; ++c) {
                const short8 bfr = *(const short8*)(&Bs[(16 * c + l16) * 72 + k2 + quad * 8]);
                acc[c] = __builtin_amdgcn_mfma_f32_16x16x32_bf16(af, bfr, acc[c], 0, 0, 0);
            }
        }
    }

#pragma unroll
    for (int c = 0; c < 4; ++c)
#pragma unroll
        for (int r = 0; r < 4; ++r) {
            const int il = 16 * w + quad * 4 + r;
            const int ol = 16 * c + l16;
            const size_t idx = ((size_t)b * Ss + it * 64 + il) * Hh + ot * 64 + ol;
            out[idx] = acc[c][r] + b2f(S[idx]);
        }
}

extern "C" void kernel_launch(void* const* d_in, const int* in_sizes, int n_in,
                              void* d_out, int out_size, void* d_ws, size_t ws_size,
                              hipStream_t stream) {
    const float* h = (const float*)d_in[0];       // [4,256,768] fp32
    const int* rels = (const int*)d_in[1];        // [4,256,256] i32
    const float* basic = (const float*)d_in[2];   // [4,768,768] fp32
    const float* relw = (const float*)d_in[3];    // [64,4] fp32
    const float* selfw = (const float*)d_in[4];   // [768,768] fp32 (out,in)
    float* out = (float*)d_out;                   // [4,256,768] fp32

    // ws layout (u16 elems, 16B-aligned)
    u16* coefC = (u16*)d_ws;                          // 1,048,576
    u16* Gt = coefC + (size_t)Bb * 4 * Ss * Ss;       // 3,145,728  [bk][o][j]
    u16* S = Gt + (size_t)Bb * 4 * Hh * Ss;           //   786,432

    k_phase1<<<1984, 256, 0, stream>>>(h, rels, basic, relw, selfw, coefC, Gt, S);
    k_phase2<<<192, 256, 0, stream>>>(coefC, Gt, S, out);
}

// Round 8
// 104.174 us; speedup vs baseline: 3.3829x; 1.0398x over previous
//
#include <hip/hip_runtime.h>
#include <stdint.h>

typedef unsigned short u16;
typedef unsigned int u32;
typedef __attribute__((ext_vector_type(8))) short short8;
typedef __attribute__((ext_vector_type(4))) float float4v;

#define Bb 4
#define Ss 256
#define Hh 768
#define NALL 64

// Inputs/outputs are FP32 (reference dtype; established r7).

__device__ __forceinline__ float b2f(u16 h) {
    u32 u = ((u32)h) << 16;
    float f;
    __builtin_memcpy(&f, &u, 4);
    return f;
}
__device__ __forceinline__ u16 f2b(float f) {
    u32 u;
    __builtin_memcpy(&u, &f, 4);
    u = (u + 0x7fffu + ((u >> 16) & 1u)) >> 16;  // RNE
    return (u16)u;
}

// ---- K0: prep — all units independent ----
//  [0,2304):    basicT[q][o][i] = bf16(basic[q][i][o])   (32x32 LDS tiles)
//  [2304,3328): coefC[b,k][i][j] build (hist + fp32 relw)
//  [3328,4096): hbf  = bf16(h)      (float4 -> 4x bf16)
//  [4096,4672): swbf = bf16(selfw)
__global__ __launch_bounds__(256) void k_prep(const float* __restrict__ h,
                                              const int* __restrict__ rels,
                                              const float* __restrict__ basic,
                                              const float* __restrict__ relw,
                                              const float* __restrict__ selfw,
                                              u16* __restrict__ basicT,
                                              u16* __restrict__ coefC,
                                              u16* __restrict__ hbf,
                                              u16* __restrict__ swbf) {
    __shared__ u16 tile[32][34];   // pad 34: transposed read stride 17 banks -> conflict-free
    __shared__ float srelw[256];
    __shared__ u32 hist[NALL];
    const int z = blockIdx.x;
    const int t = threadIdx.x;

    if (z < 2304) {                     // basic transpose + cvt
        const int q = z / 576, rem = z % 576;
        const int i0 = (rem % 24) * 32, o0 = (rem / 24) * 32;
        const int tx = t & 31, ty = t >> 5;   // 32 x 8
        const size_t base = (size_t)q * Hh * Hh;
#pragma unroll
        for (int r = 0; r < 4; ++r)
            tile[ty + 8 * r][tx] = f2b(basic[base + (size_t)(i0 + ty + 8 * r) * Hh + o0 + tx]);
        __syncthreads();
#pragma unroll
        for (int r = 0; r < 4; ++r)
            basicT[base + (size_t)(o0 + ty + 8 * r) * Hh + i0 + tx] = tile[tx][ty + 8 * r];
    } else if (z < 3328) {              // coefC build: one block per (b,i)
        const int r = z - 2304;
        const int i = r & 255, b = r >> 8;
        srelw[t] = relw[t];
        if (t < NALL) hist[t] = 0u;
        __syncthreads();
        const int rfw = rels[(b * Ss + i) * Ss + t];  // rels[b,i,t]
        const int rcl = rels[(b * Ss + t) * Ss + i];  // rels[b,t,i]
        if (rfw > 0) atomicAdd(&hist[rfw], 1u);
        if (rcl > 0) atomicAdd(&hist[rcl + 32], 1u);
        __syncthreads();
        float c0 = 0.f, c1 = 0.f, c2 = 0.f, c3 = 0.f;
        if (rfw > 0) {
            const float inv = 1.0f / (float)hist[rfw];
            c0 += srelw[rfw * 4 + 0] * inv; c1 += srelw[rfw * 4 + 1] * inv;
            c2 += srelw[rfw * 4 + 2] * inv; c3 += srelw[rfw * 4 + 3] * inv;
        }
        if (rcl > 0) {
            const int rr = rcl + 32;
            const float inv = 1.0f / (float)hist[rr];
            c0 += srelw[rr * 4 + 0] * inv; c1 += srelw[rr * 4 + 1] * inv;
            c2 += srelw[rr * 4 + 2] * inv; c3 += srelw[rr * 4 + 3] * inv;
        }
        const size_t base = ((size_t)(b * 4) * Ss + i) * Ss + t;
        coefC[base] = f2b(c0);
        coefC[base + (size_t)Ss * Ss] = f2b(c1);
        coefC[base + (size_t)2 * Ss * Ss] = f2b(c2);
        coefC[base + (size_t)3 * Ss * Ss] = f2b(c3);
    } else if (z < 4096) {              // h cvt, 4 elems/thread
        const size_t i = ((size_t)(z - 3328) * 256 + t) * 4;
        const float4 v = *(const float4*)(h + i);
        u32 lo = (u32)f2b(v.x) | ((u32)f2b(v.y) << 16);
        u32 hi = (u32)f2b(v.z) | ((u32)f2b(v.w) << 16);
        *(uint2*)(hbf + i) = make_uint2(lo, hi);
    } else {                            // selfw cvt
        const size_t i = ((size_t)(z - 4096) * 256 + t) * 4;
        const float4 v = *(const float4*)(selfw + i);
        u32 lo = (u32)f2b(v.x) | ((u32)f2b(v.y) << 16);
        u32 hi = (u32)f2b(v.z) | ((u32)f2b(v.w) << 16);
        *(uint2*)(swbf + i) = make_uint2(lo, hi);
    }
}

// ---- K1: Gt[bk][o][j] = sum_i basicT[q][o][i] * h[b][j][i] ----
// Pure bf16 GEMM: A = basicT rows (m=o), B = hbf rows (n=j), K=768.
// C/D layout writes Gt[o][j] directly — no transposed epilogue.
__global__ __launch_bounds__(256, 4) void k_mid(const u16* __restrict__ basicT,
                                                const u16* __restrict__ hbf,
                                                u16* __restrict__ Gt) {
    __shared__ __align__(16) u16 As[64 * 72];
    __shared__ __align__(16) u16 Bs[64 * 72];
    const int z = blockIdx.x;           // 12 (o-tile) x 4 (j-tile) x 16 (bk)
    const int o0 = (z % 12) * 64, j0 = ((z / 12) % 4) * 64, bk = z / 48;
    const int b = bk >> 2, q = bk & 3;
    const int t = threadIdx.x;
    const int row = t >> 2, kk = (t & 3) * 16;
    const int w = t >> 6, l = t & 63, quad = l >> 4, l16 = l & 15;

    const u16* aB = basicT + ((size_t)q * Hh + o0 + row) * Hh + kk;
    const u16* bB = hbf + ((size_t)b * Ss + j0 + row) * Hh + kk;

    float4v acc[4];
#pragma unroll
    for (int c = 0; c < 4; ++c) acc[c] = (float4v){0.f, 0.f, 0.f, 0.f};
    uint4 a0 = *(const uint4*)aB, a1 = *(const uint4*)(aB + 8);
    uint4 b0 = *(const uint4*)bB, b1 = *(const uint4*)(bB + 8);

    for (int s = 0; s < 12; ++s) {
        __syncthreads();
        *(uint4*)(&As[row * 72 + kk]) = a0;
        *(uint4*)(&As[row * 72 + kk + 8]) = a1;
        *(uint4*)(&Bs[row * 72 + kk]) = b0;
        *(uint4*)(&Bs[row * 72 + kk + 8]) = b1;
        __syncthreads();
        if (s + 1 < 12) {
            a0 = *(const uint4*)(aB + (s + 1) * 64);
            a1 = *(const uint4*)(aB + (s + 1) * 64 + 8);
            b0 = *(const uint4*)(bB + (s + 1) * 64);
            b1 = *(const uint4*)(bB + (s + 1) * 64 + 8);
        }
#pragma unroll
        for (int k2 = 0; k2 < 64; k2 += 32) {
            const short8 af = *(const short8*)(&As[(16 * w + l16) * 72 + k2 + quad * 8]);
#pragma unroll
            for (int c = 0; c < 4; ++c) {
                const short8 bfr = *(const short8*)(&Bs[(16 * c + l16) * 72 + k2 + quad * 8]);
                acc[c] = __builtin_amdgcn_mfma_f32_16x16x32_bf16(af, bfr, acc[c], 0, 0, 0);
            }
        }
    }

#pragma unroll
    for (int c = 0; c < 4; ++c)
#pragma unroll
        for (int r = 0; r < 4; ++r) {
            const int ol = 16 * w + quad * 4 + r;   // D row = m = o_local
            const int jl = 16 * c + l16;            // D col = n = j_local
            Gt[((size_t)bk * Hh + o0 + ol) * Ss + j0 + jl] = f2b(acc[c][r]);
        }
}

// ---- K2: out[b][i][o] = sum_q coefC[b,q][i]·Gt[b,q][o] (K=4*256)
//                        + hbf[b][i]·swbf[o] (K=768), fp32 out ----
__global__ __launch_bounds__(256, 4) void k_phase2(const u16* __restrict__ coefC,
                                                   const u16* __restrict__ Gt,
                                                   const u16* __restrict__ hbf,
                                                   const u16* __restrict__ swbf,
                                                   float* __restrict__ out) {
    __shared__ __align__(16) u16 As[64 * 72];
    __shared__ __align__(16) u16 Bs[64 * 72];
    const int z = blockIdx.x;           // 12 (o-tile) x 4 (i-tile) x 4 (b)
    const int ot = z % 12, it = (z / 12) % 4, b = z / 48;
    const int t = threadIdx.x;
    const int row = t >> 2, kk = (t & 3) * 16;
    const int w = t >> 6, l = t & 63, quad = l >> 4, l16 = l & 15;

    auto aa = [&](int s) -> const u16* {
        if (s < 16)
            return coefC + ((size_t)(b * 4 + (s >> 2)) * Ss + it * 64 + row) * Ss + (s & 3) * 64 + kk;
        return hbf + ((size_t)b * Ss + it * 64 + row) * Hh + (s - 16) * 64 + kk;
    };
    auto bb = [&](int s) -> const u16* {
        if (s < 16)
            return Gt + ((size_t)(b * 4 + (s >> 2)) * Hh + ot * 64 + row) * Ss + (s & 3) * 64 + kk;
        return swbf + (size_t)(ot * 64 + row) * Hh + (s - 16) * 64 + kk;
    };

    float4v acc[4];
#pragma unroll
    for (int c = 0; c < 4; ++c) acc[c] = (float4v){0.f, 0.f, 0.f, 0.f};
    uint4 a0 = *(const uint4*)aa(0);
    uint4 a1 = *(const uint4*)(aa(0) + 8);
    uint4 b0 = *(const uint4*)bb(0);
    uint4 b1 = *(const uint4*)(bb(0) + 8);

    for (int s = 0; s < 28; ++s) {
        __syncthreads();
        *(uint4*)(&As[row * 72 + kk]) = a0;
        *(uint4*)(&As[row * 72 + kk + 8]) = a1;
        *(uint4*)(&Bs[row * 72 + kk]) = b0;
        *(uint4*)(&Bs[row * 72 + kk + 8]) = b1;
        __syncthreads();
        if (s + 1 < 28) {
            const u16* ap = aa(s + 1);
            const u16* bp = bb(s + 1);
            a0 = *(const uint4*)ap;
            a1 = *(const uint4*)(ap + 8);
            b0 = *(const uint4*)bp;
            b1 = *(const uint4*)(bp + 8);
        }
#pragma unroll
        for (int k2 = 0; k2 < 64; k2 += 32) {
            const short8 af = *(const short8*)(&As[(16 * w + l16) * 72 + k2 + quad * 8]);
#pragma unroll
            for (int c = 0; c < 4; ++c) {
                const short8 bfr = *(const short8*)(&Bs[(16 * c + l16) * 72 + k2 + quad * 8]);
                acc[c] = __builtin_amdgcn_mfma_f32_16x16x32_bf16(af, bfr, acc[c], 0, 0, 0);
            }
        }
    }

#pragma unroll
    for (int c = 0; c < 4; ++c)
#pragma unroll
        for (int r = 0; r < 4; ++r) {
            const int il = 16 * w + quad * 4 + r;
            const int ol = 16 * c + l16;
            out[((size_t)b * Ss + it * 64 + il) * Hh + ot * 64 + ol] = acc[c][r];
        }
}

extern "C" void kernel_launch(void* const* d_in, const int* in_sizes, int n_in,
                              void* d_out, int out_size, void* d_ws, size_t ws_size,
                              hipStream_t stream) {
    const float* h = (const float*)d_in[0];       // [4,256,768] fp32
    const int* rels = (const int*)d_in[1];        // [4,256,256] i32
    const float* basic = (const float*)d_in[2];   // [4,768,768] fp32
    const float* relw = (const float*)d_in[3];    // [64,4] fp32
    const float* selfw = (const float*)d_in[4];   // [768,768] fp32 (out,in)
    float* out = (float*)d_out;                   // [4,256,768] fp32

    // ws layout (u16 elems, 16B-aligned)
    u16* basicT = (u16*)d_ws;                          // 2,359,296
    u16* coefC = basicT + (size_t)4 * Hh * Hh;         // 1,048,576
    u16* Gt = coefC + (size_t)Bb * 4 * Ss * Ss;        // 3,145,728  [bk][o][j]
    u16* hbf = Gt + (size_t)Bb * 4 * Hh * Ss;          //   786,432
    u16* swbf = hbf + (size_t)Bb * Ss * Hh;            //   589,824

    k_prep<<<4672, 256, 0, stream>>>(h, rels, basic, relw, selfw, basicT, coefC, hbf, swbf);
    k_mid<<<768, 256, 0, stream>>>(basicT, hbf, Gt);
    k_phase2<<<192, 256, 0, stream>>>(coefC, Gt, hbf, swbf, out);
}